// Round 7
// baseline (582.185 us; speedup 1.0000x reference)
//
#include <hip/hip_runtime.h>

#define NN 50000
#define NE 800000

typedef __attribute__((ext_vector_type(8))) short bf16x8;
typedef __attribute__((ext_vector_type(4))) float f32x4;
typedef __attribute__((ext_vector_type(2))) float f32x2;

__device__ __forceinline__ unsigned short f2bf(float f) {
    union { float f; unsigned u; } v; v.f = f;
    unsigned r = v.u + 0x7FFFu + ((v.u >> 16) & 1u);
    return (unsigned short)(r >> 16);
}

// Pack two f32 -> bf16x2 in one v_perm_b32 (round-half-up: +0x8000 then take hi16).
// V_PERM selectors: 0..3 = S1 bytes, 4..7 = S0 bytes; we want lo16=hi16(a), hi16=hi16(b).
__device__ __forceinline__ unsigned pk2bf(float a, float b) {
    unsigned ua = __float_as_uint(a) + 0x8000u;
    unsigned ub = __float_as_uint(b) + 0x8000u;
    return __builtin_amdgcn_perm(ub, ua, 0x07060302u);
}

// 32-bit-offset gathers (saddr form: uniform 64-bit base + 32-bit voffset)
__device__ __forceinline__ int4 ld_ep(const int4* ep, unsigned idx) {
    return *(const int4*)((const char*)ep + (size_t)(idx * 16u));
}
__device__ __forceinline__ float ld_x(const float* X, unsigned byteoff) {
    return *(const float*)((const char*)X + (size_t)byteoff);
}

// LDS layout (8 nodes/block): element (kstep kk, k-in-step r, node m) at word
//   kk*272 + (r>>3)*68 + m*8 + (r&7)        (68 = 64 data + 4 pad, 16B-aligned)
__device__ __forceinline__ int widx(int kk, int r, int m) {
    return kk*272 + (r >> 3)*68 + m*8 + (r & 7);
}

// MFMA A-fragment: lane holds A[m = lane&15][k = qq*8 + j]; rows 8..15 are zero.
__device__ __forceinline__ bf16x8 afrag(const float* hb, int kk, int m, int qq) {
    bf16x8 av = (bf16x8){0,0,0,0,0,0,0,0};
    if (m < 8) {
        const float* p = &hb[kk*272 + qq*68 + m*8];
        float4 a0 = *(const float4*)p;
        float4 a1 = *(const float4*)(p + 4);
        union { unsigned u[4]; bf16x8 v; } au;
        au.u[0] = pk2bf(a0.x, a0.y);
        au.u[1] = pk2bf(a0.z, a0.w);
        au.u[2] = pk2bf(a1.x, a1.y);
        au.u[3] = pk2bf(a1.z, a1.w);
        av = au.v;
    }
    return av;
}

// hat-basis accumulate for TWO edges packed into f32x2 lanes (v_pk_fma_f32 path).
template<bool HS>
__device__ __forceinline__ void edge_acc2(f32x2* h2, f32x2& hs2,
                                          const int4& pa, const int4& pb,
                                          float xa, float xb) {
    const f32x2 zero = {0.f, 0.f};
    f32x2 vp0 = {__int_as_float(pa.z), __int_as_float(pb.z)};
    f32x2 vp1 = {__int_as_float(pa.w), __int_as_float(pb.w)};
    f32x2 xp  = {xa, xb};
    if (HS) hs2 += xp;
    f32x2 wx[5], wy[5];
#pragma unroll
    for (int r = 0; r < 5; ++r) {
        f32x2 w0 = 1.f - __builtin_elementwise_abs(vp0 - (float)r);
        f32x2 w1 = 1.f - __builtin_elementwise_abs(vp1 - (float)r);
        wx[r] = __builtin_elementwise_max(w0, zero);
        wy[r] = __builtin_elementwise_max(w1, zero);
    }
#pragma unroll
    for (int r1 = 0; r1 < 5; ++r1) {
        f32x2 ty = xp * wy[r1];
#pragma unroll
        for (int r0 = 0; r0 < 5; ++r0)
            h2[r1*5 + r0] = __builtin_elementwise_fma(wx[r0], ty, h2[r1*5 + r0]);
    }
}

// ---------------- setup kernels ----------------
__global__ __launch_bounds__(256) void k_zero(int* degi, int* cur, float* stats) {
    int i = blockIdx.x*256 + threadIdx.x;
    int stride = gridDim.x*256;
    for (int j = i; j < NN; j += stride) { degi[j] = 0; cur[j] = 0; }
    if (i < 384) stats[i] = 0.f;
}

__global__ __launch_bounds__(256) void k_hist(const int* __restrict__ dst, int* degi) {
    int e = blockIdx.x*256 + threadIdx.x;
    if (e < NE) atomicAdd(&degi[dst[e]], 1);
}

__global__ __launch_bounds__(256) void k_scan_block(const int* __restrict__ degi,
                                                    int* off, int* bsum) {
    __shared__ int sh[256];
    int t = threadIdx.x;
    int base = blockIdx.x * 1024;
    int v[4]; int s = 0;
#pragma unroll
    for (int j = 0; j < 4; j++) {
        int idx = base + t*4 + j;
        v[j] = (idx < NN) ? degi[idx] : 0;
        s += v[j];
    }
    sh[t] = s; __syncthreads();
    for (int ofs = 1; ofs < 256; ofs <<= 1) {
        int x = (t >= ofs) ? sh[t - ofs] : 0;
        __syncthreads();
        sh[t] += x;
        __syncthreads();
    }
    int ex = sh[t] - s;
#pragma unroll
    for (int j = 0; j < 4; j++) {
        int idx = base + t*4 + j;
        if (idx < NN) off[idx] = ex;
        ex += v[j];
    }
    if (t == 255) bsum[blockIdx.x] = sh[255];
}

__global__ __launch_bounds__(256) void k_scan_top(const int* __restrict__ bsum,
                                                  int* bpre, int nb) {
    __shared__ int sh[256];
    int t = threadIdx.x;
    int s = (t < nb) ? bsum[t] : 0;
    sh[t] = s; __syncthreads();
    for (int ofs = 1; ofs < 256; ofs <<= 1) {
        int x = (t >= ofs) ? sh[t - ofs] : 0;
        __syncthreads();
        sh[t] += x;
        __syncthreads();
    }
    if (t < nb) bpre[t] = sh[t] - s;
}

__global__ __launch_bounds__(256) void k_scan_add(int* off, const int* __restrict__ bpre) {
    int i = blockIdx.x*256 + threadIdx.x;
    if (i < NN) off[i] += bpre[i >> 10];
    if (i == 0) off[NN] = NE;
}

// ep = (src, 0, v0, v1) with v = pseudo*4 in [0,4); hat weights derive from v.
__global__ __launch_bounds__(256) void k_scatter(const int* __restrict__ src,
                                                 const int* __restrict__ dst,
                                                 const float* __restrict__ ea,
                                                 const int* __restrict__ off, int* cur,
                                                 int4* __restrict__ ep) {
    int e = blockIdx.x*256 + threadIdx.x;
    if (e >= NE) return;
    int d = dst[e];
    int p = off[d] + atomicAdd(&cur[d], 1);
    float v0 = ea[2*e]     * 4.f;
    float v1 = ea[2*e + 1] * 4.f;
    ep[p] = make_int4(src[e], 0, __float_as_int(v0), __float_as_int(v1));
}

// Pre-tile [W ; root] (f32, row-major [K,64]) into MFMA-B bf16 layout:
// Wb[((kk*4+cot)*64+lane)*8 + j] = src[k = kk*32+(lane>>4)*8+j][co = 16*cot+(lane&15)]
__global__ __launch_bounds__(256) void k_wprep(const float* __restrict__ W,
                                               const float* __restrict__ root,
                                               int KTC, unsigned short* Wb) {
    int tid = blockIdx.x*256 + threadIdx.x;
    int lane = tid & 63, cot = (tid >> 6) & 3, kk = tid >> 8;
    int co = 16*cot + (lane & 15);
    int kbase = kk*32 + ((lane >> 4) * 8);
    union { unsigned short s[8]; uint4 v; } u;
#pragma unroll
    for (int j = 0; j < 8; j++) {
        int k = kbase + j;
        float val = (k < KTC) ? W[(size_t)k*64 + co] : root[(size_t)(k - KTC)*64 + co];
        u.s[j] = f2bf(val);
    }
    *(uint4*)(Wb + (size_t)tid * 8) = u.v;
}

// ---------------- conv1 + convS fused: register buckets, R1-style phase B ----
// 8 nodes/block, 4 waves; half-wave per node; lane&31 = ci.
__global__ __launch_bounds__(256, 4) void k_conv1s(
        const float* __restrict__ X,
        const int* __restrict__ off,
        const int4* __restrict__ ep,
        const unsigned short* __restrict__ Wb1,
        const unsigned short* __restrict__ WbS,
        const float* __restrict__ b1,
        const float* __restrict__ bs,
        float* __restrict__ agg1,
        float* __restrict__ aggS) {
    __shared__ __align__(16) float hb[28*272];   // ksteps: 25 wi, x, hs, x
    const int t = threadIdx.x, lane = t & 63, w = t >> 6;
    const int ci = lane & 31;
    const int g = 2*w + (lane >> 5);
    const int n0 = blockIdx.x * 8;
    const int n = n0 + g;

    f32x2 h2[25], hs2 = {0.f, 0.f};
#pragma unroll
    for (int i = 0; i < 25; ++i) h2[i] = (f32x2){0.f, 0.f};

    const int ebeg = off[n], eend = off[n + 1];
    const int last = eend - 1;
    const float rdeg = 1.f / (float)max(eend - ebeg, 1);

    for (int i = ebeg; i < eend; i += 4) {
        int4 p[4]; float xv[4];
#pragma unroll
        for (int u = 0; u < 4; ++u) p[u] = ld_ep(ep, (unsigned)min(i + u, last));
#pragma unroll
        for (int u = 0; u < 4; ++u) {
            xv[u] = ld_x(X, (unsigned)p[u].x * 128u + (unsigned)ci * 4u);
            if (i + u >= eend) xv[u] = 0.f;
        }
        edge_acc2<true>(h2, hs2, p[0], p[1], xv[0], xv[1]);
        edge_acc2<true>(h2, hs2, p[2], p[3], xv[2], xv[3]);
    }

    // ---- dump: kstep idx = wi (k = wi*32 + ci); 25 = x; 26 = hs; 27 = x ----
    const int bw = widx(0, ci, g);
    const float xself = X[(size_t)n*32 + ci];
#pragma unroll
    for (int idx = 0; idx < 25; ++idx)
        hb[idx*272 + bw] = (h2[idx].x + h2[idx].y) * rdeg;
    hb[25*272 + bw] = xself;
    hb[26*272 + bw] = (hs2.x + hs2.y) * rdeg;
    hb[27*272 + bw] = xself;
    __syncthreads();

    // ---- phase B: full K per wave, co-tile w ----
    const int m = lane & 15, qq = lane >> 4;
    f32x4 acc  = {0.f, 0.f, 0.f, 0.f};
    f32x4 accs = {0.f, 0.f, 0.f, 0.f};
    for (int kk = 0; kk < 26; ++kk) {
        bf16x8 av = afrag(hb, kk, m, qq);
        bf16x8 bv = *(const bf16x8*)(Wb1 + (size_t)((kk*4 + w)*64 + lane) * 8);
        acc = __builtin_amdgcn_mfma_f32_16x16x32_bf16(av, bv, acc, 0, 0, 0);
    }
#pragma unroll
    for (int s = 0; s < 2; ++s) {
        bf16x8 av = afrag(hb, 26 + s, m, qq);
        bf16x8 bv = *(const bf16x8*)(WbS + (size_t)((s*4 + w)*64 + lane) * 8);
        accs = __builtin_amdgcn_mfma_f32_16x16x32_bf16(av, bv, accs, 0, 0, 0);
    }

    // ---- store (C/D: col=lane&15, row=qq*4+r); rows 0..7 are the nodes ----
    const int co = w*16 + m;
    const float bb1 = b1[co], bbs = bs[co];
#pragma unroll
    for (int r = 0; r < 4; ++r) {
        int row = qq*4 + r;
        if (row < 8) {
            agg1[(size_t)(n0 + row)*64 + co] = acc[r] + bb1;
            aggS[(size_t)(n0 + row)*64 + co] = accs[r] + bbs;
        }
    }
}

// ---------------- conv2: register buckets, two dump/MFMA passes ----------------
// 8 nodes/block, wave w owns nodes 2w, 2w+1 sequentially; lane = ci (0..63).
__global__ __launch_bounds__(256, 4) void k_conv2(
        const float* __restrict__ X,
        const int* __restrict__ off,
        const int4* __restrict__ ep,
        const unsigned short* __restrict__ Wb2,
        const float* __restrict__ b2,
        float* __restrict__ agg) {
    __shared__ __align__(16) float hb[26*272];
    const int t = threadIdx.x, lane = t & 63, w = t >> 6;
    const int n0 = blockIdx.x * 8;

    float h[2][25];
#pragma unroll
    for (int nn = 0; nn < 2; ++nn) {
        const int n = n0 + 2*w + nn;
        const int ebeg = off[n], eend = off[n + 1];
        const int last = eend - 1;
        const float rdeg = 1.f / (float)max(eend - ebeg, 1);
        f32x2 h2[25], hsd = {0.f, 0.f};
#pragma unroll
        for (int i = 0; i < 25; ++i) h2[i] = (f32x2){0.f, 0.f};
        for (int i = ebeg; i < eend; i += 4) {
            int4 p[4]; float xv[4];
#pragma unroll
            for (int u = 0; u < 4; ++u) p[u] = ld_ep(ep, (unsigned)min(i + u, last));
#pragma unroll
            for (int u = 0; u < 4; ++u) {
                xv[u] = ld_x(X, (unsigned)p[u].x * 256u + (unsigned)lane * 4u);
                if (i + u >= eend) xv[u] = 0.f;
            }
            edge_acc2<false>(h2, hsd, p[0], p[1], xv[0], xv[1]);
            edge_acc2<false>(h2, hsd, p[2], p[3], xv[2], xv[3]);
        }
#pragma unroll
        for (int i = 0; i < 25; ++i) h[nn][i] = (h2[i].x + h2[i].y) * rdeg;
    }

    // k-mapping: global k = wi*64 + ci; kstep = wi*2 + (ci>>5); r = ci&31.
    const int kh = lane >> 5, r = lane & 31;
    const int m = lane & 15, qq = lane >> 4;
    f32x4 acc = {0.f, 0.f, 0.f, 0.f};

    // ---- pass 0: wi 0..12 -> local ksteps 0..25 = global 0..25 ----
#pragma unroll
    for (int wi = 0; wi < 13; ++wi)
#pragma unroll
        for (int nn = 0; nn < 2; ++nn)
            hb[widx(wi*2 + kh, r, 2*w + nn)] = h[nn][wi];
    __syncthreads();
    for (int kk = 0; kk < 26; ++kk) {
        bf16x8 av = afrag(hb, kk, m, qq);
        bf16x8 bv = *(const bf16x8*)(Wb2 + (size_t)((kk*4 + w)*64 + lane) * 8);
        acc = __builtin_amdgcn_mfma_f32_16x16x32_bf16(av, bv, acc, 0, 0, 0);
    }
    __syncthreads();

    // ---- pass 1: wi 13..24 (local 0..23) + x (local 24,25) = global 26..51 ----
#pragma unroll
    for (int wi = 13; wi < 25; ++wi)
#pragma unroll
        for (int nn = 0; nn < 2; ++nn)
            hb[widx((wi - 13)*2 + kh, r, 2*w + nn)] = h[nn][wi];
#pragma unroll
    for (int nn = 0; nn < 2; ++nn)
        hb[widx(24 + kh, r, 2*w + nn)] = X[(size_t)(n0 + 2*w + nn)*64 + lane];
    __syncthreads();
    for (int kk = 0; kk < 26; ++kk) {
        bf16x8 av = afrag(hb, kk, m, qq);
        bf16x8 bv = *(const bf16x8*)(Wb2 + (size_t)(((26 + kk)*4 + w)*64 + lane) * 8);
        acc = __builtin_amdgcn_mfma_f32_16x16x32_bf16(av, bv, acc, 0, 0, 0);
    }

    // ---- store ----
    const int co = w*16 + m;
    const float bb = b2[co];
#pragma unroll
    for (int rr = 0; rr < 4; ++rr) {
        int row = qq*4 + rr;
        if (row < 8)
            agg[(size_t)(n0 + row)*64 + co] = acc[rr] + bb;
    }
}

// ---------------- batch norm ----------------
__global__ __launch_bounds__(256) void k_bnstats(const float* __restrict__ agg, float* stats) {
    __shared__ float sh0[256], sh1[256];
    int t = threadIdx.x;
    float s = 0.f, ss = 0.f;
    int stride = gridDim.x * 256;
    for (int i = blockIdx.x*256 + t; i < NN*64; i += stride) {
        float v = agg[i];
        s += v; ss += v*v;
    }
    sh0[t] = s; sh1[t] = ss;
    __syncthreads();
    if (t < 64) {
        float a = sh0[t] + sh0[t+64] + sh0[t+128] + sh0[t+192];
        float b = sh1[t] + sh1[t+64] + sh1[t+128] + sh1[t+192];
        atomicAdd(&stats[t], a);
        atomicAdd(&stats[64 + t], b);
    }
}

__device__ __forceinline__ float eluf(float u) { return u > 0.f ? u : expm1f(u); }

__global__ __launch_bounds__(256) void k_bn_elu(const float* __restrict__ agg,
                                                const float* __restrict__ stats,
                                                const float* __restrict__ gamma,
                                                const float* __restrict__ beta,
                                                float* __restrict__ out) {
    int i = blockIdx.x*256 + threadIdx.x;
    if (i >= NN*16) return;
    float4 v = ((const float4*)agg)[i];
    float r[4] = {v.x, v.y, v.z, v.w};
    int c0 = (i << 2) & 63;
#pragma unroll
    for (int j = 0; j < 4; j++) {
        int c = c0 + j;
        float mu = stats[c] * (1.f/NN);
        float var = stats[64 + c] * (1.f/NN) - mu*mu;
        float sc = gamma[c] * rsqrtf(fmaxf(var, 0.f) + 1e-5f);
        r[j] = eluf((r[j] - mu)*sc + beta[c]);
    }
    ((float4*)out)[i] = make_float4(r[0], r[1], r[2], r[3]);
}

__global__ __launch_bounds__(256) void k_bn_final(const float* __restrict__ a2,
                                                  const float* __restrict__ st2,
                                                  const float* __restrict__ g2,
                                                  const float* __restrict__ be2,
                                                  const float* __restrict__ as,
                                                  const float* __restrict__ sts,
                                                  const float* __restrict__ gs,
                                                  const float* __restrict__ bes,
                                                  float* __restrict__ out) {
    int i = blockIdx.x*256 + threadIdx.x;
    if (i >= NN*16) return;
    float4 v2 = ((const float4*)a2)[i];
    float4 vs = ((const float4*)as)[i];
    float r2v[4] = {v2.x, v2.y, v2.z, v2.w};
    float rsv[4] = {vs.x, vs.y, vs.z, vs.w};
    float o[4];
    int c0 = (i << 2) & 63;
#pragma unroll
    for (int j = 0; j < 4; j++) {
        int c = c0 + j;
        float mu2 = st2[c] * (1.f/NN);
        float var2 = st2[64 + c] * (1.f/NN) - mu2*mu2;
        float sc2 = g2[c] * rsqrtf(fmaxf(var2, 0.f) + 1e-5f);
        float mus = sts[c] * (1.f/NN);
        float vars = sts[64 + c] * (1.f/NN) - mus*mus;
        float scs = gs[c] * rsqrtf(fmaxf(vars, 0.f) + 1e-5f);
        float u = (r2v[j] - mu2)*sc2 + be2[c] + (rsv[j] - mus)*scs + bes[c];
        o[j] = eluf(u);
    }
    ((float4*)out)[i] = make_float4(o[0], o[1], o[2], o[3]);
}

extern "C" void kernel_launch(void* const* d_in, const int* in_sizes, int n_in,
                              void* d_out, int out_size, void* d_ws, size_t ws_size,
                              hipStream_t stream) {
    const float* x   = (const float*)d_in[0];
    const int*   ei  = (const int*)d_in[1];
    const float* ea  = (const float*)d_in[2];
    const float* w1  = (const float*)d_in[3];
    const float* r1  = (const float*)d_in[4];
    const float* b1  = (const float*)d_in[5];
    const float* g1  = (const float*)d_in[6];
    const float* be1 = (const float*)d_in[7];
    const float* w2  = (const float*)d_in[8];
    const float* r2  = (const float*)d_in[9];
    const float* b2  = (const float*)d_in[10];
    const float* g2  = (const float*)d_in[11];
    const float* be2 = (const float*)d_in[12];
    const float* wsN = (const float*)d_in[13];
    const float* rs  = (const float*)d_in[14];
    const float* bs  = (const float*)d_in[15];
    const float* gs  = (const float*)d_in[16];
    const float* bes = (const float*)d_in[17];
    const int* srcp = ei;
    const int* dstp = ei + NE;

    char* wsb = (char*)d_ws;
    size_t o = 0;
    auto alloc = [&](size_t bytes) -> char* {
        char* p = wsb + o;
        o += (bytes + 255) & ~(size_t)255;
        return p;
    };
    int*    degi    = (int*)   alloc((size_t)NN * 4);
    int*    cur     = (int*)   alloc((size_t)NN * 4);
    int*    off     = (int*)   alloc((size_t)(NN + 1) * 4);
    int*    bsum    = (int*)   alloc(256 * 4);
    int*    bpre    = (int*)   alloc(256 * 4);
    int4*   ep      = (int4*)  alloc((size_t)NE * 16);
    unsigned short* Wb1 = (unsigned short*)alloc(26 * 4096);
    unsigned short* WbS = (unsigned short*)alloc(2 * 4096);
    unsigned short* Wb2 = (unsigned short*)alloc(52 * 4096);
    float*  agg1    = (float*) alloc((size_t)NN * 64 * 4);  // reused for conv2 output
    float*  aggS    = (float*) alloc((size_t)NN * 64 * 4);
    float*  h1      = (float*) alloc((size_t)NN * 64 * 4);
    float*  stats   = (float*) alloc(384 * 4);
    (void)ws_size; (void)in_sizes; (void)n_in; (void)out_size;

    float* out = (float*)d_out;

    k_zero<<<196, 256, 0, stream>>>(degi, cur, stats);
    k_hist<<<3125, 256, 0, stream>>>(dstp, degi);
    k_scan_block<<<49, 256, 0, stream>>>(degi, off, bsum);
    k_scan_top<<<1, 256, 0, stream>>>(bsum, bpre, 49);
    k_scan_add<<<196, 256, 0, stream>>>(off, bpre);
    k_scatter<<<3125, 256, 0, stream>>>(srcp, dstp, ea, off, cur, ep);

    k_wprep<<<26, 256, 0, stream>>>(w1, r1, 800, Wb1);
    k_wprep<<<2, 256, 0, stream>>>(wsN, rs, 32, WbS);
    k_wprep<<<52, 256, 0, stream>>>(w2, r2, 1600, Wb2);

    k_conv1s<<<6250, 256, 0, stream>>>(x, off, ep, Wb1, WbS, b1, bs, agg1, aggS);
    k_bnstats<<<256, 256, 0, stream>>>(agg1, stats);
    k_bn_elu<<<3125, 256, 0, stream>>>(agg1, stats, g1, be1, h1);

    k_conv2<<<6250, 256, 0, stream>>>(h1, off, ep, Wb2, b2, agg1);
    k_bnstats<<<256, 256, 0, stream>>>(agg1, stats + 128);
    k_bnstats<<<256, 256, 0, stream>>>(aggS, stats + 256);
    k_bn_final<<<3125, 256, 0, stream>>>(agg1, stats + 128, g2, be2,
                                         aggS, stats + 256, gs, bes, out);
}

// Round 8
// 481.468 us; speedup vs baseline: 1.2092x; 1.2092x over previous
//
#include <hip/hip_runtime.h>

#define NN 50000
#define NE 800000

typedef __attribute__((ext_vector_type(8))) short bf16x8;
typedef __attribute__((ext_vector_type(4))) float f32x4;
typedef __attribute__((ext_vector_type(2))) float f32x2;

__device__ __forceinline__ unsigned short f2bf(float f) {
    union { float f; unsigned u; } v; v.f = f;
    unsigned r = v.u + 0x7FFFu + ((v.u >> 16) & 1u);
    return (unsigned short)(r >> 16);
}

// 32-bit-offset gathers (uniform 64-bit base + 32-bit voffset)
__device__ __forceinline__ int4 ld_ep(const int4* ep, unsigned idx) {
    return *(const int4*)((const char*)ep + (size_t)(idx * 16u));
}
__device__ __forceinline__ float ld_x(const float* X, unsigned byteoff) {
    return *(const float*)((const char*)X + (size_t)byteoff);
}

// bf16 LDS A-fragment layout (16 nodes/block):
//   element (kstep kk, r = k&31, node m) at ushort index
//   kk*544 + (r>>3)*136 + m*8 + (r&7)
// afrag load for lane(m,qq): 16B at kk*544 + qq*136 + m*8  -> k = qq*8+j. 2-way banks.
__device__ __forceinline__ int us_idx(int kk, int r, int m) {
    return kk*544 + (r >> 3)*136 + m*8 + (r & 7);
}

// packed hat-weight accumulate: h[25] += x * wx(r0) * wy(r1); optional hs += x.
template<bool HS>
__device__ __forceinline__ void edge_acc(float* h, float& hs, const int4& p, float x) {
    const f32x2 zero = {0.f, 0.f};
    f32x2 vp = {__int_as_float(p.z), __int_as_float(p.w)};
    f32x2 wxy[5];
#pragma unroll
    for (int r = 0; r < 5; ++r) {
        f32x2 wr = 1.f - __builtin_elementwise_abs(vp - (float)r);
        wxy[r] = __builtin_elementwise_max(wr, zero);
    }
    if (HS) hs += x;
#pragma unroll
    for (int r1 = 0; r1 < 5; ++r1) {
        float ty = x * wxy[r1].y;
#pragma unroll
        for (int r0 = 0; r0 < 5; ++r0)
            h[r1*5 + r0] = fmaf(wxy[r0].x, ty, h[r1*5 + r0]);
    }
}

// ---------------- setup kernels ----------------
__global__ __launch_bounds__(256) void k_zero(int* degi, int* cur, float* stats) {
    int i = blockIdx.x*256 + threadIdx.x;
    int stride = gridDim.x*256;
    for (int j = i; j < NN; j += stride) { degi[j] = 0; cur[j] = 0; }
    if (i < 384) stats[i] = 0.f;
}

__global__ __launch_bounds__(256) void k_hist(const int* __restrict__ dst, int* degi) {
    int e = blockIdx.x*256 + threadIdx.x;
    if (e < NE) atomicAdd(&degi[dst[e]], 1);
}

__global__ __launch_bounds__(256) void k_scan_block(const int* __restrict__ degi,
                                                    int* off, int* bsum) {
    __shared__ int sh[256];
    int t = threadIdx.x;
    int base = blockIdx.x * 1024;
    int v[4]; int s = 0;
#pragma unroll
    for (int j = 0; j < 4; j++) {
        int idx = base + t*4 + j;
        v[j] = (idx < NN) ? degi[idx] : 0;
        s += v[j];
    }
    sh[t] = s; __syncthreads();
    for (int ofs = 1; ofs < 256; ofs <<= 1) {
        int x = (t >= ofs) ? sh[t - ofs] : 0;
        __syncthreads();
        sh[t] += x;
        __syncthreads();
    }
    int ex = sh[t] - s;
#pragma unroll
    for (int j = 0; j < 4; j++) {
        int idx = base + t*4 + j;
        if (idx < NN) off[idx] = ex;
        ex += v[j];
    }
    if (t == 255) bsum[blockIdx.x] = sh[255];
}

__global__ __launch_bounds__(256) void k_scan_top(const int* __restrict__ bsum,
                                                  int* bpre, int nb) {
    __shared__ int sh[256];
    int t = threadIdx.x;
    int s = (t < nb) ? bsum[t] : 0;
    sh[t] = s; __syncthreads();
    for (int ofs = 1; ofs < 256; ofs <<= 1) {
        int x = (t >= ofs) ? sh[t - ofs] : 0;
        __syncthreads();
        sh[t] += x;
        __syncthreads();
    }
    if (t < nb) bpre[t] = sh[t] - s;
}

__global__ __launch_bounds__(256) void k_scan_add(int* off, const int* __restrict__ bpre) {
    int i = blockIdx.x*256 + threadIdx.x;
    if (i < NN) off[i] += bpre[i >> 10];
    if (i == 0) off[NN] = NE;
}

// ep = (src, 0, v0, v1) with v = pseudo*4 in [0,4); hat weights derive from v.
__global__ __launch_bounds__(256) void k_scatter(const int* __restrict__ src,
                                                 const int* __restrict__ dst,
                                                 const float* __restrict__ ea,
                                                 const int* __restrict__ off, int* cur,
                                                 int4* __restrict__ ep) {
    int e = blockIdx.x*256 + threadIdx.x;
    if (e >= NE) return;
    int d = dst[e];
    int p = off[d] + atomicAdd(&cur[d], 1);
    float v0 = ea[2*e]     * 4.f;
    float v1 = ea[2*e + 1] * 4.f;
    ep[p] = make_int4(src[e], 0, __float_as_int(v0), __float_as_int(v1));
}

// Pre-tile [W ; root] (f32, row-major [K,64]) into MFMA-B bf16 layout:
// Wb[((kk*4+cot)*64+lane)*8 + j] = src[k = kk*32+(lane>>4)*8+j][co = 16*cot+(lane&15)]
__global__ __launch_bounds__(256) void k_wprep(const float* __restrict__ W,
                                               const float* __restrict__ root,
                                               int KTC, unsigned short* Wb) {
    int tid = blockIdx.x*256 + threadIdx.x;
    int lane = tid & 63, cot = (tid >> 6) & 3, kk = tid >> 8;
    int co = 16*cot + (lane & 15);
    int kbase = kk*32 + ((lane >> 4) * 8);
    union { unsigned short s[8]; uint4 v; } u;
#pragma unroll
    for (int j = 0; j < 8; j++) {
        int k = kbase + j;
        float val = (k < KTC) ? W[(size_t)k*64 + co] : root[(size_t)(k - KTC)*64 + co];
        u.s[j] = f2bf(val);
    }
    *(uint4*)(Wb + (size_t)tid * 8) = u.v;
}

// ---------------- conv1 + convS fused: 16 nodes/block, bf16 LDS fragments ----
// 512 threads, 8 waves. Half-wave (t>>5) owns node g; ci = t&31.
// Phase B: waves 0-3 -> agg1 co-tile w (26 ksteps); waves 4-7 -> aggS (2 ksteps).
__global__ __launch_bounds__(512, 4) void k_conv1s(
        const float* __restrict__ X,
        const int* __restrict__ off,
        const int4* __restrict__ ep,
        const unsigned short* __restrict__ Wb1,
        const unsigned short* __restrict__ WbS,
        const float* __restrict__ b1,
        const float* __restrict__ bs,
        float* __restrict__ agg1,
        float* __restrict__ aggS) {
    __shared__ __align__(16) unsigned short hb[28*544];  // 30.5 KB
    const int t = threadIdx.x;
    const int g = t >> 5;          // node slot 0..15
    const int ci = t & 31;
    const int n0 = blockIdx.x * 16;
    const int n = n0 + g;

    float h[25], hs = 0.f;
#pragma unroll
    for (int i = 0; i < 25; ++i) h[i] = 0.f;

    const int ebeg = off[n], eend = off[n + 1];
    const int last = eend - 1;
    const float rdeg = 1.f / (float)max(eend - ebeg, 1);

    for (int i = ebeg; i < eend; i += 4) {
        int4 p[4]; float xv[4];
#pragma unroll
        for (int u = 0; u < 4; ++u) p[u] = ld_ep(ep, (unsigned)min(i + u, last));
#pragma unroll
        for (int u = 0; u < 4; ++u) {
            xv[u] = ld_x(X, (unsigned)p[u].x * 128u + (unsigned)ci * 4u);
            if (i + u >= eend) xv[u] = 0.f;
        }
#pragma unroll
        for (int u = 0; u < 4; ++u) edge_acc<true>(h, hs, p[u], xv[u]);
    }

    // ---- dump bf16 fragments: kstep = wi; 25 = x; 26 = hs; 27 = x ----
    const int bw = us_idx(0, ci, g);
    const unsigned short xbf = f2bf(X[(size_t)n*32 + ci]);
#pragma unroll
    for (int wi = 0; wi < 25; ++wi) hb[wi*544 + bw] = f2bf(h[wi] * rdeg);
    hb[25*544 + bw] = xbf;
    hb[26*544 + bw] = f2bf(hs * rdeg);
    hb[27*544 + bw] = xbf;
    __syncthreads();

    // ---- phase B ----
    const int lane = t & 63, w = t >> 6;
    const int m = lane & 15, qq = lane >> 4;
    const int co = (w & 3)*16 + m;
    if (w < 4) {
        f32x4 acc = {0.f, 0.f, 0.f, 0.f};
        for (int kk = 0; kk < 26; ++kk) {
            bf16x8 av = *(const bf16x8*)&hb[kk*544 + qq*136 + m*8];
            bf16x8 bv = *(const bf16x8*)(Wb1 + (size_t)((kk*4 + w)*64 + lane) * 8);
            acc = __builtin_amdgcn_mfma_f32_16x16x32_bf16(av, bv, acc, 0, 0, 0);
        }
        const float bb = b1[co];
#pragma unroll
        for (int r = 0; r < 4; ++r)
            agg1[(size_t)(n0 + qq*4 + r)*64 + co] = acc[r] + bb;
    } else {
        f32x4 accs = {0.f, 0.f, 0.f, 0.f};
#pragma unroll
        for (int s = 0; s < 2; ++s) {
            bf16x8 av = *(const bf16x8*)&hb[(26 + s)*544 + qq*136 + m*8];
            bf16x8 bv = *(const bf16x8*)(WbS + (size_t)((s*4 + (w & 3))*64 + lane) * 8);
            accs = __builtin_amdgcn_mfma_f32_16x16x32_bf16(av, bv, accs, 0, 0, 0);
        }
        const float bb = bs[co];
#pragma unroll
        for (int r = 0; r < 4; ++r)
            aggS[(size_t)(n0 + qq*4 + r)*64 + co] = accs[r] + bb;
    }
}

// ---------------- conv2: 16 nodes/block, bf16 LDS fragments ----------------
// 512 threads, 8 waves. Wave w owns nodes 2w, 2w+1 sequentially; lane = ci 0..63.
// Phase B: waves 0-3 full 52 ksteps, co-tile w; waves 4-7 exit after barrier.
__global__ __launch_bounds__(512, 4) void k_conv2(
        const float* __restrict__ X,
        const int* __restrict__ off,
        const int4* __restrict__ ep,
        const unsigned short* __restrict__ Wb2,
        const float* __restrict__ b2,
        float* __restrict__ agg) {
    __shared__ __align__(16) unsigned short hb[52*544];  // 56.6 KB
    const int t = threadIdx.x, lane = t & 63, w = t >> 6;
    const int n0 = blockIdx.x * 16;
    const int kh = lane >> 5, r = lane & 31;   // k = wi*64 + lane -> kstep wi*2+kh

#pragma unroll
    for (int nn = 0; nn < 2; ++nn) {
        const int g = 2*w + nn;
        const int n = n0 + g;
        float h[25];
#pragma unroll
        for (int i = 0; i < 25; ++i) h[i] = 0.f;
        float hsd = 0.f;

        const int ebeg = off[n], eend = off[n + 1];
        const int last = eend - 1;
        const float rdeg = 1.f / (float)max(eend - ebeg, 1);

        for (int i = ebeg; i < eend; i += 4) {
            int4 p[4]; float xv[4];
#pragma unroll
            for (int u = 0; u < 4; ++u) p[u] = ld_ep(ep, (unsigned)min(i + u, last));
#pragma unroll
            for (int u = 0; u < 4; ++u) {
                xv[u] = ld_x(X, (unsigned)p[u].x * 256u + (unsigned)lane * 4u);
                if (i + u >= eend) xv[u] = 0.f;
            }
#pragma unroll
            for (int u = 0; u < 4; ++u) edge_acc<false>(h, hsd, p[u], xv[u]);
        }

        // dump: wi 0..24 -> ksteps wi*2+kh; x -> ksteps 50,51
        const int bw = us_idx(0, r, g);
#pragma unroll
        for (int wi = 0; wi < 25; ++wi)
            hb[(wi*2 + kh)*544 + bw] = f2bf(h[wi] * rdeg);
        hb[(50 + kh)*544 + bw] = f2bf(X[(size_t)n*64 + lane]);
    }
    __syncthreads();

    if (w >= 4) return;

    const int m = lane & 15, qq = lane >> 4;
    f32x4 acc = {0.f, 0.f, 0.f, 0.f};
    for (int kk = 0; kk < 52; ++kk) {
        bf16x8 av = *(const bf16x8*)&hb[kk*544 + qq*136 + m*8];
        bf16x8 bv = *(const bf16x8*)(Wb2 + (size_t)((kk*4 + w)*64 + lane) * 8);
        acc = __builtin_amdgcn_mfma_f32_16x16x32_bf16(av, bv, acc, 0, 0, 0);
    }
    const int co = w*16 + m;
    const float bb = b2[co];
#pragma unroll
    for (int rr = 0; rr < 4; ++rr)
        agg[(size_t)(n0 + qq*4 + rr)*64 + co] = acc[rr] + bb;
}

// ---------------- batch norm ----------------
__global__ __launch_bounds__(256) void k_bnstats(const float* __restrict__ agg, float* stats) {
    __shared__ float sh0[256], sh1[256];
    int t = threadIdx.x;
    float s = 0.f, ss = 0.f;
    int stride = gridDim.x * 256;
    for (int i = blockIdx.x*256 + t; i < NN*64; i += stride) {
        float v = agg[i];
        s += v; ss += v*v;
    }
    sh0[t] = s; sh1[t] = ss;
    __syncthreads();
    if (t < 64) {
        float a = sh0[t] + sh0[t+64] + sh0[t+128] + sh0[t+192];
        float b = sh1[t] + sh1[t+64] + sh1[t+128] + sh1[t+192];
        atomicAdd(&stats[t], a);
        atomicAdd(&stats[64 + t], b);
    }
}

__device__ __forceinline__ float eluf(float u) { return u > 0.f ? u : expm1f(u); }

__global__ __launch_bounds__(256) void k_bn_elu(const float* __restrict__ agg,
                                                const float* __restrict__ stats,
                                                const float* __restrict__ gamma,
                                                const float* __restrict__ beta,
                                                float* __restrict__ out) {
    int i = blockIdx.x*256 + threadIdx.x;
    if (i >= NN*16) return;
    float4 v = ((const float4*)agg)[i];
    float r[4] = {v.x, v.y, v.z, v.w};
    int c0 = (i << 2) & 63;
#pragma unroll
    for (int j = 0; j < 4; j++) {
        int c = c0 + j;
        float mu = stats[c] * (1.f/NN);
        float var = stats[64 + c] * (1.f/NN) - mu*mu;
        float sc = gamma[c] * rsqrtf(fmaxf(var, 0.f) + 1e-5f);
        r[j] = eluf((r[j] - mu)*sc + beta[c]);
    }
    ((float4*)out)[i] = make_float4(r[0], r[1], r[2], r[3]);
}

__global__ __launch_bounds__(256) void k_bn_final(const float* __restrict__ a2,
                                                  const float* __restrict__ st2,
                                                  const float* __restrict__ g2,
                                                  const float* __restrict__ be2,
                                                  const float* __restrict__ as,
                                                  const float* __restrict__ sts,
                                                  const float* __restrict__ gs,
                                                  const float* __restrict__ bes,
                                                  float* __restrict__ out) {
    int i = blockIdx.x*256 + threadIdx.x;
    if (i >= NN*16) return;
    float4 v2 = ((const float4*)a2)[i];
    float4 vs = ((const float4*)as)[i];
    float r2v[4] = {v2.x, v2.y, v2.z, v2.w};
    float rsv[4] = {vs.x, vs.y, vs.z, vs.w};
    float o[4];
    int c0 = (i << 2) & 63;
#pragma unroll
    for (int j = 0; j < 4; j++) {
        int c = c0 + j;
        float mu2 = st2[c] * (1.f/NN);
        float var2 = st2[64 + c] * (1.f/NN) - mu2*mu2;
        float sc2 = g2[c] * rsqrtf(fmaxf(var2, 0.f) + 1e-5f);
        float mus = sts[c] * (1.f/NN);
        float vars = sts[64 + c] * (1.f/NN) - mus*mus;
        float scs = gs[c] * rsqrtf(fmaxf(vars, 0.f) + 1e-5f);
        float u = (r2v[j] - mu2)*sc2 + be2[c] + (rsv[j] - mus)*scs + bes[c];
        o[j] = eluf(u);
    }
    ((float4*)out)[i] = make_float4(o[0], o[1], o[2], o[3]);
}

extern "C" void kernel_launch(void* const* d_in, const int* in_sizes, int n_in,
                              void* d_out, int out_size, void* d_ws, size_t ws_size,
                              hipStream_t stream) {
    const float* x   = (const float*)d_in[0];
    const int*   ei  = (const int*)d_in[1];
    const float* ea  = (const float*)d_in[2];
    const float* w1  = (const float*)d_in[3];
    const float* r1  = (const float*)d_in[4];
    const float* b1  = (const float*)d_in[5];
    const float* g1  = (const float*)d_in[6];
    const float* be1 = (const float*)d_in[7];
    const float* w2  = (const float*)d_in[8];
    const float* r2  = (const float*)d_in[9];
    const float* b2  = (const float*)d_in[10];
    const float* g2  = (const float*)d_in[11];
    const float* be2 = (const float*)d_in[12];
    const float* wsN = (const float*)d_in[13];
    const float* rs  = (const float*)d_in[14];
    const float* bs  = (const float*)d_in[15];
    const float* gs  = (const float*)d_in[16];
    const float* bes = (const float*)d_in[17];
    const int* srcp = ei;
    const int* dstp = ei + NE;

    char* wsb = (char*)d_ws;
    size_t o = 0;
    auto alloc = [&](size_t bytes) -> char* {
        char* p = wsb + o;
        o += (bytes + 255) & ~(size_t)255;
        return p;
    };
    int*    degi    = (int*)   alloc((size_t)NN * 4);
    int*    cur     = (int*)   alloc((size_t)NN * 4);
    int*    off     = (int*)   alloc((size_t)(NN + 1) * 4);
    int*    bsum    = (int*)   alloc(256 * 4);
    int*    bpre    = (int*)   alloc(256 * 4);
    int4*   ep      = (int4*)  alloc((size_t)NE * 16);
    unsigned short* Wb1 = (unsigned short*)alloc(26 * 4096);
    unsigned short* WbS = (unsigned short*)alloc(2 * 4096);
    unsigned short* Wb2 = (unsigned short*)alloc(52 * 4096);
    float*  agg1    = (float*) alloc((size_t)NN * 64 * 4);  // reused for conv2 output
    float*  aggS    = (float*) alloc((size_t)NN * 64 * 4);
    float*  h1      = (float*) alloc((size_t)NN * 64 * 4);
    float*  stats   = (float*) alloc(384 * 4);
    (void)ws_size; (void)in_sizes; (void)n_in; (void)out_size;

    float* out = (float*)d_out;

    k_zero<<<196, 256, 0, stream>>>(degi, cur, stats);
    k_hist<<<3125, 256, 0, stream>>>(dstp, degi);
    k_scan_block<<<49, 256, 0, stream>>>(degi, off, bsum);
    k_scan_top<<<1, 256, 0, stream>>>(bsum, bpre, 49);
    k_scan_add<<<196, 256, 0, stream>>>(off, bpre);
    k_scatter<<<3125, 256, 0, stream>>>(srcp, dstp, ea, off, cur, ep);

    k_wprep<<<26, 256, 0, stream>>>(w1, r1, 800, Wb1);
    k_wprep<<<2, 256, 0, stream>>>(wsN, rs, 32, WbS);
    k_wprep<<<52, 256, 0, stream>>>(w2, r2, 1600, Wb2);

    k_conv1s<<<3125, 512, 0, stream>>>(x, off, ep, Wb1, WbS, b1, bs, agg1, aggS);
    k_bnstats<<<256, 256, 0, stream>>>(agg1, stats);
    k_bn_elu<<<3125, 256, 0, stream>>>(agg1, stats, g1, be1, h1);

    k_conv2<<<3125, 512, 0, stream>>>(h1, off, ep, Wb2, b2, agg1);
    k_bnstats<<<256, 256, 0, stream>>>(agg1, stats + 128);
    k_bnstats<<<256, 256, 0, stream>>>(aggS, stats + 256);
    k_bn_final<<<3125, 256, 0, stream>>>(agg1, stats + 128, g2, be2,
                                         aggS, stats + 256, gs, bes, out);
}